// Round 12
// baseline (189.930 us; speedup 1.0000x reference)
//
#include <hip/hip_runtime.h>
#include <hip/hip_bf16.h>

#define B_TOT 131072
#define D     32
#define H1    50
#define QF    528      // tril feature count
#define H2    700
#define MROWS 32       // batch rows per tile
#define KITER 18       // K = 576 = 528 quad | 1 bias-one | 32 y | 15 pad
#define TILES 8        // persistent: row-tiles per block (grid = 4096/8 = 512)
// extended hidden layout (768 cols): 0..699 = net2 hidden, 700..749 = net1 hidden,
// 750 = bias channel (h==1.0 exactly), 751..767 = zero pad

typedef __attribute__((ext_vector_type(8))) short  short8x;
typedef __attribute__((ext_vector_type(4))) float  floatx4;

static __device__ __forceinline__ unsigned short f2bf(float f) {
    __hip_bfloat16 h = __float2bfloat16(f);   // RNE
    return __builtin_bit_cast(unsigned short, h);
}
static __device__ __forceinline__ float bf2f(unsigned short u) {
    unsigned int x = (unsigned int)u << 16;
    return __builtin_bit_cast(float, x);
}
// clampless tanh: exp2 overflow->+inf -> rcp(inf)=0 -> 1; underflow->0 -> -1.
// MUST stay bit-identical between prep (bias channel) and fused epilogue.
static __device__ __forceinline__ float tanh_fast(float x) {
    float e = __builtin_amdgcn_exp2f(x * 2.885390082f);   // e^(2x)
    return 1.f - 2.f * __builtin_amdgcn_rcpf(e + 1.f);
}

// ---------------- prep: extended pre-fragmented bf16 weight layouts (unchanged r11) ----
// W2aT: [k=0..17][panel p=0..47][lane 0..63][j 0..7]  (442368 ushorts)
//   B1[kk][c], kk = k*32+(lane>>4)*8+j, c = p*16+(lane&15):
//     c<700: kk<528 -> W2a[kk][c]; kk==528 -> b2a[c]
//     c<750: kk==528 -> b1a[c-700]; 529<=kk<561 -> W1a[kk-529][c-700]
//     c==750: kk==528 -> 1.0
// W2bT: [wave w][ks 0..1][of 0..1][lane][j] (32768 ushorts)
//   B2[kg][c], kg = w*48 + kl: kg<700 -> W2b; kg<750 -> W1b[kg-700];
//   kg==750 -> (b1b[c]+b2b[c]) / tanh_fast(1.0)
__global__ void prep_kernel(const float* __restrict__ W2a, const float* __restrict__ b2a,
                            const float* __restrict__ W2b,
                            const float* __restrict__ W1a, const float* __restrict__ b1a,
                            const float* __restrict__ W1b, const float* __restrict__ b1b,
                            const float* __restrict__ b2b,
                            unsigned short* __restrict__ W2aT,
                            unsigned short* __restrict__ W2bT) {
    int idx = blockIdx.x * 256 + threadIdx.x;
    const int N1 = KITER * 48 * 512;   // 442368
    const int N2 = 16 * 4 * 512;       // 32768
    if (idx < N1) {
        int k   = idx / (48 * 512);
        int rem = idx - k * (48 * 512);
        int p   = rem >> 9;
        int q   = rem & 511;
        int ln  = q >> 3, j = q & 7;
        int kk  = k * 32 + ((ln >> 4) << 3) + j;
        int c   = (p << 4) + (ln & 15);
        float v = 0.f;
        if (c < H2) {
            if (kk < QF)       v = W2a[kk * H2 + c];
            else if (kk == QF) v = b2a[c];
        } else if (c < H2 + H1) {
            int cc = c - H2;
            if (kk == QF)                        v = b1a[cc];
            else if (kk > QF && kk < QF + 1 + D) v = W1a[(kk - QF - 1) * H1 + cc];
        } else if (c == H2 + H1) {
            if (kk == QF) v = 1.0f;
        }
        W2aT[idx] = f2bf(v);
    } else if (idx < N1 + N2) {
        int i2 = idx - N1;
        int q  = i2 & 511;
        int ln = q >> 3, j = q & 7;
        int w  = i2 >> 11;
        int ks = (i2 >> 10) & 1;
        int of = (i2 >> 9) & 1;
        int kl = (ks << 5) + ((ln >> 4) << 3) + j;   // local k 0..63
        int kg = w * 48 + kl;
        int c  = (of << 4) + (ln & 15);
        float v = 0.f;
        if (kl < 48) {
            if (kg < H2)            v = W2b[kg * D + c];
            else if (kg < H2 + H1)  v = W1b[(kg - H2) * D + c];
            else if (kg == H2 + H1) v = (b1b[c] + b2b[c]) / tanh_fast(1.0f);
        }
        W2bT[i2] = f2bf(v);
    }
}

// ---------------- fused main kernel ----------------
// r11 structure + (a) A stored in MFMA-fragment layout quadA[k][tile][lane][8]
// -> K-loop ds_read_b128 is one contiguous 1KB per frag, zero bank conflicts
// (r11's stride-584 layout was ~2-way conflicted: 1.3e7 conflict cycles);
// (b) persistent blocks: grid=512 (exactly 2/CU), 8 row-tiles per block ->
// kills 7/8 of per-generation pipeline head/tail drain.
__global__ __launch_bounds__(1024, 8)
__attribute__((amdgpu_waves_per_eu(8, 8)))
void fused_kernel(
    const float* __restrict__ y,
    const unsigned short* __restrict__ W2aT, const unsigned short* __restrict__ W2bT,
    float* __restrict__ out) {

    __shared__ unsigned short quadA[KITER][2][512]; // 36864 B; post-K reused as bf16 stage [16][1024]
    __shared__ float          yls[MROWS][36];       //  4608 B
    __shared__ unsigned short hst[16][16][68];      // 34816 B  => total 76288 B (2 blocks/CU)

    const int tid  = threadIdx.x;
    const int lane = tid & 63;
    const int w    = tid >> 6;                         // wave 0..15
    const int wu   = __builtin_amdgcn_readfirstlane(w);
    const int l15  = lane & 15;
    const int lg   = lane >> 4;                        // 0..3
    unsigned short* stage = &quadA[0][0][0];

    // hst K-pad cols 48..63 zero (epilogue only writes 0..47; zeros persist)
    {
        int rr = lane >> 2, cc0 = 48 + (lane & 3) * 4;
        *reinterpret_cast<unsigned long long*>(&hst[w][rr][cc0]) = 0ULL;
    }

    for (int t = 0; t < TILES; ++t) {
        const int row0 = (blockIdx.x * TILES + t) * MROWS;

        // ---- Phase A: y tile (coalesced). Barrier also orders prev-tile
        // reduce reads (stage == quadA region) before this tile's A build.
        yls[tid >> 5][tid & 31] = y[row0 * D + tid];
        __syncthreads();

        // ---- Phase B: A build directly in fragment layout ----
        // (r,kk) -> ushort idx = rbase + ((kk>>5)<<10) + ((kk&24)<<4) + (kk&7)
        //   rbase = ((r>>4)<<9) + ((r&15)<<3)
        {
            int r = tid >> 5, i = tid & 31;
            int rbase = ((r >> 4) << 9) + ((r & 15) << 3);
            int base  = (i * (i + 1)) >> 1;
            float yi  = yls[r][i];
            for (int j4 = 0; j4 <= i; j4 += 4) {
                floatx4 yv = *reinterpret_cast<const floatx4*>(&yls[r][j4]);
                #pragma unroll
                for (int jj = 0; jj < 4; ++jj) {
                    int j = j4 + jj;
                    if (j <= i) {
                        int kk = base + j;
                        stage[rbase + ((kk >> 5) << 10) + ((kk & 24) << 4) + (kk & 7)]
                            = f2bf(yi * yv[jj]);
                    }
                }
            }
            {   // y channel kk = 529+i
                int kk = 529 + i;
                stage[rbase + ((kk >> 5) << 10) + ((kk & 24) << 4) + (kk & 7)] = f2bf(yi);
            }
            if (i == 0)   // bias-one channel kk = 528
                stage[rbase + ((528 >> 5) << 10) + ((528 & 24) << 4)] = (unsigned short)0x3F80;
            if (i < 15) { // zero pad kk = 561..575
                int kk = 561 + i;
                stage[rbase + ((kk >> 5) << 10) + ((kk & 24) << 4) + (kk & 7)] = 0;
            }
        }
        __syncthreads();

        // ---- K-loop: wave w owns hidden cols [w*48, w*48+48), K = 576 ----
        floatx4 hacc00 = {0,0,0,0}, hacc01 = {0,0,0,0}, hacc02 = {0,0,0,0};
        floatx4 hacc10 = {0,0,0,0}, hacc11 = {0,0,0,0}, hacc12 = {0,0,0,0};
        {
            const unsigned short* bp = W2aT + wu * 3 * 512 + lane * 8;
            const unsigned short* ap = &quadA[0][0][lane * 8];
            #pragma unroll 1
            for (int k = 0; k < KITER; ++k) {
                short8x a0 = *reinterpret_cast<const short8x*>(ap);
                short8x a1 = *reinterpret_cast<const short8x*>(ap + 512);
                short8x b0 = *reinterpret_cast<const short8x*>(bp);
                short8x b1 = *reinterpret_cast<const short8x*>(bp + 512);
                short8x b2 = *reinterpret_cast<const short8x*>(bp + 1024);
                hacc00 = __builtin_amdgcn_mfma_f32_16x16x32_bf16(a0, b0, hacc00, 0, 0, 0);
                hacc01 = __builtin_amdgcn_mfma_f32_16x16x32_bf16(a0, b1, hacc01, 0, 0, 0);
                hacc02 = __builtin_amdgcn_mfma_f32_16x16x32_bf16(a0, b2, hacc02, 0, 0, 0);
                hacc10 = __builtin_amdgcn_mfma_f32_16x16x32_bf16(a1, b0, hacc10, 0, 0, 0);
                hacc11 = __builtin_amdgcn_mfma_f32_16x16x32_bf16(a1, b1, hacc11, 0, 0, 0);
                hacc12 = __builtin_amdgcn_mfma_f32_16x16x32_bf16(a1, b2, hacc12, 0, 0, 0);
                ap += 1024;
                bp += 48 * 512;
            }
        }
        __syncthreads();   // all quadA K-reads complete -> stage region free

        // ---- epilogue: tanh -> hst -> GEMM2 (transient o2) -> packed bf16 stage ----
        // stage layout: flat f = row*32 + 2*l15 + of  holds col (of*16 + l15)
        {
            const unsigned short* wb = W2bT + wu * 4 * 512 + lane * 8;
            #pragma unroll
            for (int m = 0; m < 2; ++m) {
                const floatx4 h0 = m ? hacc10 : hacc00;
                const floatx4 h1 = m ? hacc11 : hacc01;
                const floatx4 h2 = m ? hacc12 : hacc02;
                #pragma unroll
                for (int r = 0; r < 4; ++r) {
                    hst[w][lg * 4 + r][l15]      = f2bf(tanh_fast(h0[r]));
                    hst[w][lg * 4 + r][16 + l15] = f2bf(tanh_fast(h1[r]));
                    hst[w][lg * 4 + r][32 + l15] = f2bf(tanh_fast(h2[r]));
                }
                short8x aa0 = *reinterpret_cast<const short8x*>(&hst[w][l15][lg * 8]);
                short8x aa1 = *reinterpret_cast<const short8x*>(&hst[w][l15][32 + lg * 8]);
                floatx4 o20 = {0,0,0,0}, o21 = {0,0,0,0};
                {
                    short8x bw00 = *reinterpret_cast<const short8x*>(wb);
                    short8x bw01 = *reinterpret_cast<const short8x*>(wb + 512);
                    o20 = __builtin_amdgcn_mfma_f32_16x16x32_bf16(aa0, bw00, o20, 0, 0, 0);
                    o21 = __builtin_amdgcn_mfma_f32_16x16x32_bf16(aa0, bw01, o21, 0, 0, 0);
                }
                {
                    short8x bw10 = *reinterpret_cast<const short8x*>(wb + 1024);
                    short8x bw11 = *reinterpret_cast<const short8x*>(wb + 1536);
                    o20 = __builtin_amdgcn_mfma_f32_16x16x32_bf16(aa1, bw10, o20, 0, 0, 0);
                    o21 = __builtin_amdgcn_mfma_f32_16x16x32_bf16(aa1, bw11, o21, 0, 0, 0);
                }
                #pragma unroll
                for (int r = 0; r < 4; ++r) {
                    int row = m * 16 + lg * 4 + r;
                    unsigned int pk = ((unsigned int)f2bf(o21[r]) << 16) | (unsigned int)f2bf(o20[r]);
                    *reinterpret_cast<unsigned int*>(&stage[wu * 1024 + row * 32 + l15 * 2]) = pk;
                }
            }
        }
        __syncthreads();   // all stage writes visible

        // ---- reduce 16 bf16 panels (biases inside via col-750 channel) ----
        {
            int c  = tid & 31;
            int fr = (tid & ~31) + ((c & 15) << 1) + (c >> 4);   // packed-layout remap
            float s0 = 0.f, s1 = 0.f;
            #pragma unroll
            for (int p = 0; p < 16; p += 2) {
                s0 += bf2f(stage[p * 1024 + fr]);
                s1 += bf2f(stage[(p + 1) * 1024 + fr]);
            }
            out[row0 * D + tid] = s0 + s1;
        }
        // next-iter Phase-A barrier orders these reduce reads vs next A build
    }
}

extern "C" void kernel_launch(void* const* d_in, const int* in_sizes, int n_in,
                              void* d_out, int out_size, void* d_ws, size_t ws_size,
                              hipStream_t stream) {
    const float* y   = (const float*)d_in[1];
    const float* W1a = (const float*)d_in[2];
    const float* b1a = (const float*)d_in[3];
    const float* W1b = (const float*)d_in[4];
    const float* b1b = (const float*)d_in[5];
    const float* W2a = (const float*)d_in[6];
    const float* b2a = (const float*)d_in[7];
    const float* W2b = (const float*)d_in[8];
    const float* b2b = (const float*)d_in[9];

    unsigned short* W2aT = (unsigned short*)d_ws;                      // 884736 B
    unsigned short* W2bT = (unsigned short*)((char*)d_ws + 884736);    //  65536 B

    const int prep_tasks = KITER * 48 * 512 + 16 * 4 * 512;            // 475136
    prep_kernel<<<(prep_tasks + 255) / 256, 256, 0, stream>>>(
        W2a, b2a, W2b, W1a, b1a, W1b, b1b, b2b, W2aT, W2bT);
    fused_kernel<<<B_TOT / (MROWS * TILES), 1024, 0, stream>>>(y, W2aT, W2bT, (float*)d_out);
}

// Round 13
// 152.067 us; speedup vs baseline: 1.2490x; 1.2490x over previous
//
#include <hip/hip_runtime.h>
#include <hip/hip_bf16.h>

#define B_TOT 131072
#define D     32
#define H1    50
#define QF    528      // tril feature count
#define H2    700
#define MROWS 64       // batch rows per block (halves W2aT L2 traffic vs 32)
#define QSTR  584      // quadls row stride (ushorts)
#define KITER 18       // K = 576 = 528 quad | 1 bias-one | 32 y | 15 pad
// extended hidden layout (768 cols): 0..699 net2 hidden, 700..749 net1 hidden,
// 750 bias channel (h==1.0), 751..767 zero pad

typedef __attribute__((ext_vector_type(8))) short  short8x;
typedef __attribute__((ext_vector_type(4))) float  floatx4;

static __device__ __forceinline__ unsigned short f2bf(float f) {
    __hip_bfloat16 h = __float2bfloat16(f);   // RNE
    return __builtin_bit_cast(unsigned short, h);
}
static __device__ __forceinline__ float bf2f(unsigned short u) {
    unsigned int x = (unsigned int)u << 16;
    return __builtin_bit_cast(float, x);
}
// clampless tanh; MUST stay bit-identical between prep (bias channel) and epilogue.
static __device__ __forceinline__ float tanh_fast(float x) {
    float e = __builtin_amdgcn_exp2f(x * 2.885390082f);   // e^(2x)
    return 1.f - 2.f * __builtin_amdgcn_rcpf(e + 1.f);
}

// ---------------- prep: extended pre-fragmented bf16 weight layouts (r11, unchanged) ----
__global__ void prep_kernel(const float* __restrict__ W2a, const float* __restrict__ b2a,
                            const float* __restrict__ W2b,
                            const float* __restrict__ W1a, const float* __restrict__ b1a,
                            const float* __restrict__ W1b, const float* __restrict__ b1b,
                            const float* __restrict__ b2b,
                            unsigned short* __restrict__ W2aT,
                            unsigned short* __restrict__ W2bT) {
    int idx = blockIdx.x * 256 + threadIdx.x;
    const int N1 = KITER * 48 * 512;   // 442368
    const int N2 = 16 * 4 * 512;       // 32768
    if (idx < N1) {
        int k   = idx / (48 * 512);
        int rem = idx - k * (48 * 512);
        int p   = rem >> 9;
        int q   = rem & 511;
        int ln  = q >> 3, j = q & 7;
        int kk  = k * 32 + ((ln >> 4) << 3) + j;
        int c   = (p << 4) + (ln & 15);
        float v = 0.f;
        if (c < H2) {
            if (kk < QF)       v = W2a[kk * H2 + c];
            else if (kk == QF) v = b2a[c];
        } else if (c < H2 + H1) {
            int cc = c - H2;
            if (kk == QF)                        v = b1a[cc];
            else if (kk > QF && kk < QF + 1 + D) v = W1a[(kk - QF - 1) * H1 + cc];
        } else if (c == H2 + H1) {
            if (kk == QF) v = 1.0f;
        }
        W2aT[idx] = f2bf(v);
    } else if (idx < N1 + N2) {
        int i2 = idx - N1;
        int q  = i2 & 511;
        int ln = q >> 3, j = q & 7;
        int w  = i2 >> 11;
        int ks = (i2 >> 10) & 1;
        int of = (i2 >> 9) & 1;
        int kl = (ks << 5) + ((ln >> 4) << 3) + j;   // local k 0..63
        int kg = w * 48 + kl;
        int c  = (of << 4) + (ln & 15);
        float v = 0.f;
        if (kl < 48) {
            if (kg < H2)            v = W2b[kg * D + c];
            else if (kg < H2 + H1)  v = W1b[(kg - H2) * D + c];
            else if (kg == H2 + H1) v = (b1b[c] + b2b[c]) / tanh_fast(1.0f);
        }
        W2bT[i2] = f2bf(v);
    }
}

// ---------------- fused main kernel ----------------
// Round-13: M=64 rows per block -> W2aT streamed once per 64 rows (L2 traffic
// 3.6 GB -> 1.8 GB, the dominant pipe at r11). Needs hacc[4][3] = 48 VGPRs ->
// 128-reg budget -> waves_per_eu(4,4), 1 block/CU (LDS 118.8 KB). r12's two
// regressions reverted: row-major A build (frag-layout scatter writes were
// MORE conflicted) and no block persistence (it thrashed W2aT out of L2:
// FETCH 12->66 MB).
__global__ __launch_bounds__(1024)
__attribute__((amdgpu_waves_per_eu(4, 4)))
void fused_kernel(
    const float* __restrict__ y,
    const unsigned short* __restrict__ W2aT, const unsigned short* __restrict__ W2bT,
    float* __restrict__ out) {

    __shared__ unsigned short quadls[MROWS][QSTR]; // 74752 B; post-K reused as bf16 stage [16][2048]
    __shared__ float          yls[MROWS][36];      //  9216 B
    __shared__ unsigned short hst[16][16][68];     // 34816 B  => total 118784 B (1 block/CU)

    const int tid  = threadIdx.x;
    const int lane = tid & 63;
    const int w    = tid >> 6;                         // wave 0..15
    const int wu   = __builtin_amdgcn_readfirstlane(w);
    const int l15  = lane & 15;
    const int lg   = lane >> 4;                        // 0..3
    const int row0 = blockIdx.x * MROWS;
    unsigned short* stage = &quadls[0][0];

    // ---- Phase A: y tile (2 floats/thread, coalesced); zero hst pad cols ----
    yls[tid >> 5][tid & 31] = y[row0 * D + tid];
    yls[32 + (tid >> 5)][tid & 31] = y[row0 * D + 1024 + tid];
    {
        int rr = lane >> 2, cc0 = 48 + (lane & 3) * 4;
        *reinterpret_cast<unsigned long long*>(&hst[w][rr][cc0]) = 0ULL;
    }
    __syncthreads();

    // ---- Phase B: A build (2 (row,i) tasks/thread): quad | 1.0 | y | pad ----
    #pragma unroll
    for (int s = 0; s < 2; ++s) {
        int task = tid + s * 1024;
        int r = task >> 5, i = task & 31;
        int base = (i * (i + 1)) >> 1;
        float yi = yls[r][i];
        for (int j4 = 0; j4 <= i; j4 += 4) {
            floatx4 yv = *reinterpret_cast<const floatx4*>(&yls[r][j4]);
            #pragma unroll
            for (int jj = 0; jj < 4; ++jj) {
                int j = j4 + jj;
                if (j <= i) quadls[r][base + j] = f2bf(yi * yv[jj]);
            }
        }
        quadls[r][529 + i] = f2bf(yi);                         // y channels 529..560
        if (i == 0)  quadls[r][528] = (unsigned short)0x3F80;  // bias-one channel
        if (i < 15)  quadls[r][561 + i] = 0;                   // K-pad 561..575
    }
    __syncthreads();

    // ---- K-loop: wave w owns hidden cols [w*48, w*48+48) x 64 rows, K=576 ----
    floatx4 hacc[4][3];
    #pragma unroll
    for (int m = 0; m < 4; ++m)
        #pragma unroll
        for (int nf = 0; nf < 3; ++nf) hacc[m][nf] = (floatx4){0.f, 0.f, 0.f, 0.f};
    {
        const unsigned short* bp = W2aT + wu * 3 * 512 + lane * 8;
        #pragma unroll 2
        for (int k = 0; k < KITER; ++k) {
            short8x a[4];
            #pragma unroll
            for (int m = 0; m < 4; ++m)
                a[m] = *reinterpret_cast<const short8x*>(&quadls[m * 16 + l15][k * 32 + lg * 8]);
            short8x b0 = *reinterpret_cast<const short8x*>(bp);
            short8x b1 = *reinterpret_cast<const short8x*>(bp + 512);
            short8x b2 = *reinterpret_cast<const short8x*>(bp + 1024);
            #pragma unroll
            for (int m = 0; m < 4; ++m) {
                hacc[m][0] = __builtin_amdgcn_mfma_f32_16x16x32_bf16(a[m], b0, hacc[m][0], 0, 0, 0);
                hacc[m][1] = __builtin_amdgcn_mfma_f32_16x16x32_bf16(a[m], b1, hacc[m][1], 0, 0, 0);
                hacc[m][2] = __builtin_amdgcn_mfma_f32_16x16x32_bf16(a[m], b2, hacc[m][2], 0, 0, 0);
            }
            bp += 48 * 512;
        }
    }
    __syncthreads();   // all quadls K-reads complete -> stage region free

    // ---- epilogue: per m-tile: tanh -> hst -> GEMM2 (transient o2) -> packed stage ----
    // stage layout: panel wu (2048 ushorts): flat = row*32 + 2*l15 + of
    {
        const unsigned short* wb = W2bT + wu * 4 * 512 + lane * 8;
        #pragma unroll
        for (int m = 0; m < 4; ++m) {
            #pragma unroll
            for (int r = 0; r < 4; ++r) {
                hst[w][lg * 4 + r][l15]      = f2bf(tanh_fast(hacc[m][0][r]));
                hst[w][lg * 4 + r][16 + l15] = f2bf(tanh_fast(hacc[m][1][r]));
                hst[w][lg * 4 + r][32 + l15] = f2bf(tanh_fast(hacc[m][2][r]));
            }
            short8x aa0 = *reinterpret_cast<const short8x*>(&hst[w][l15][lg * 8]);
            short8x aa1 = *reinterpret_cast<const short8x*>(&hst[w][l15][32 + lg * 8]);
            floatx4 o20 = {0,0,0,0}, o21 = {0,0,0,0};
            {
                short8x bw00 = *reinterpret_cast<const short8x*>(wb);
                short8x bw01 = *reinterpret_cast<const short8x*>(wb + 512);
                o20 = __builtin_amdgcn_mfma_f32_16x16x32_bf16(aa0, bw00, o20, 0, 0, 0);
                o21 = __builtin_amdgcn_mfma_f32_16x16x32_bf16(aa0, bw01, o21, 0, 0, 0);
            }
            {
                short8x bw10 = *reinterpret_cast<const short8x*>(wb + 1024);
                short8x bw11 = *reinterpret_cast<const short8x*>(wb + 1536);
                o20 = __builtin_amdgcn_mfma_f32_16x16x32_bf16(aa1, bw10, o20, 0, 0, 0);
                o21 = __builtin_amdgcn_mfma_f32_16x16x32_bf16(aa1, bw11, o21, 0, 0, 0);
            }
            #pragma unroll
            for (int r = 0; r < 4; ++r) {
                int row = m * 16 + lg * 4 + r;
                unsigned int pk = ((unsigned int)f2bf(o21[r]) << 16) | (unsigned int)f2bf(o20[r]);
                *reinterpret_cast<unsigned int*>(&stage[wu * 2048 + row * 32 + l15 * 2]) = pk;
            }
        }
    }
    __syncthreads();   // all stage writes visible

    // ---- reduce 16 bf16 panels (biases inside), 2 outputs/thread ----
    {
        #pragma unroll
        for (int s = 0; s < 2; ++s) {
            int e  = tid + s * 1024;
            int c  = e & 31;
            int fr = (e & ~31) + ((c & 15) << 1) + (c >> 4);   // packed-layout remap
            float s0 = 0.f, s1 = 0.f;
            #pragma unroll
            for (int p = 0; p < 16; p += 2) {
                s0 += bf2f(stage[p * 2048 + fr]);
                s1 += bf2f(stage[(p + 1) * 2048 + fr]);
            }
            out[row0 * D + e] = s0 + s1;
        }
    }
}

extern "C" void kernel_launch(void* const* d_in, const int* in_sizes, int n_in,
                              void* d_out, int out_size, void* d_ws, size_t ws_size,
                              hipStream_t stream) {
    const float* y   = (const float*)d_in[1];
    const float* W1a = (const float*)d_in[2];
    const float* b1a = (const float*)d_in[3];
    const float* W1b = (const float*)d_in[4];
    const float* b1b = (const float*)d_in[5];
    const float* W2a = (const float*)d_in[6];
    const float* b2a = (const float*)d_in[7];
    const float* W2b = (const float*)d_in[8];
    const float* b2b = (const float*)d_in[9];

    unsigned short* W2aT = (unsigned short*)d_ws;                      // 884736 B
    unsigned short* W2bT = (unsigned short*)((char*)d_ws + 884736);    //  65536 B

    const int prep_tasks = KITER * 48 * 512 + 16 * 4 * 512;            // 475136
    prep_kernel<<<(prep_tasks + 255) / 256, 256, 0, stream>>>(
        W2a, b2a, W2b, W1a, b1a, W1b, b1b, b2b, W2aT, W2bT);
    fused_kernel<<<B_TOT / MROWS, 1024, 0, stream>>>(y, W2aT, W2bT, (float*)d_out);
}

// Round 14
// 150.187 us; speedup vs baseline: 1.2646x; 1.0125x over previous
//
#include <hip/hip_runtime.h>
#include <hip/hip_bf16.h>

#define B_TOT 131072
#define D     32
#define H1    50
#define QF    528      // tril feature count
#define H2    700
#define MROWS 64       // batch rows per block (W2aT streamed once per 64 rows)
#define QSTR  584      // quadls row stride (ushorts)
#define KITER 18       // K = 576 = 528 quad | 1 bias-one | 32 y | 15 pad
// extended hidden layout (768 cols): 0..699 net2 hidden, 700..749 net1 hidden,
// 750 bias channel (h==1.0), 751..767 zero pad

typedef __attribute__((ext_vector_type(8))) short  short8x;
typedef __attribute__((ext_vector_type(4))) float  floatx4;

static __device__ __forceinline__ unsigned short f2bf(float f) {
    __hip_bfloat16 h = __float2bfloat16(f);   // RNE
    return __builtin_bit_cast(unsigned short, h);
}
static __device__ __forceinline__ float bf2f(unsigned short u) {
    unsigned int x = (unsigned int)u << 16;
    return __builtin_bit_cast(float, x);
}
// clampless tanh; MUST stay bit-identical between prep (bias channel) and epilogue.
static __device__ __forceinline__ float tanh_fast(float x) {
    float e = __builtin_amdgcn_exp2f(x * 2.885390082f);   // e^(2x)
    return 1.f - 2.f * __builtin_amdgcn_rcpf(e + 1.f);
}

// ---------------- prep: extended pre-fragmented bf16 weight layouts (r11, unchanged) ----
__global__ void prep_kernel(const float* __restrict__ W2a, const float* __restrict__ b2a,
                            const float* __restrict__ W2b,
                            const float* __restrict__ W1a, const float* __restrict__ b1a,
                            const float* __restrict__ W1b, const float* __restrict__ b1b,
                            const float* __restrict__ b2b,
                            unsigned short* __restrict__ W2aT,
                            unsigned short* __restrict__ W2bT) {
    int idx = blockIdx.x * 256 + threadIdx.x;
    const int N1 = KITER * 48 * 512;   // 442368
    const int N2 = 16 * 4 * 512;       // 32768
    if (idx < N1) {
        int k   = idx / (48 * 512);
        int rem = idx - k * (48 * 512);
        int p   = rem >> 9;
        int q   = rem & 511;
        int ln  = q >> 3, j = q & 7;
        int kk  = k * 32 + ((ln >> 4) << 3) + j;
        int c   = (p << 4) + (ln & 15);
        float v = 0.f;
        if (c < H2) {
            if (kk < QF)       v = W2a[kk * H2 + c];
            else if (kk == QF) v = b2a[c];
        } else if (c < H2 + H1) {
            int cc = c - H2;
            if (kk == QF)                        v = b1a[cc];
            else if (kk > QF && kk < QF + 1 + D) v = W1a[(kk - QF - 1) * H1 + cc];
        } else if (c == H2 + H1) {
            if (kk == QF) v = 1.0f;
        }
        W2aT[idx] = f2bf(v);
    } else if (idx < N1 + N2) {
        int i2 = idx - N1;
        int q  = i2 & 511;
        int ln = q >> 3, j = q & 7;
        int w  = i2 >> 11;
        int ks = (i2 >> 10) & 1;
        int of = (i2 >> 9) & 1;
        int kl = (ks << 5) + ((ln >> 4) << 3) + j;   // local k 0..63
        int kg = w * 48 + kl;
        int c  = (of << 4) + (ln & 15);
        float v = 0.f;
        if (kl < 48) {
            if (kg < H2)            v = W2b[kg * D + c];
            else if (kg < H2 + H1)  v = W1b[(kg - H2) * D + c];
            else if (kg == H2 + H1) v = (b1b[c] + b2b[c]) / tanh_fast(1.0f);
        }
        W2bT[i2] = f2bf(v);
    }
}

// ---------------- fused main kernel ----------------
// r13 + 3-deep software-pipelined B prefetch in the K-loop (named registers,
// no runtime-indexed arrays). r13 diagnosis: K-loop is L2-LATENCY-bound
// (unroll-2 left <=6 loads in flight; dispatch-level L2 util only 34%).
// 9 B-frags resident; loads for k+3 issued after k's MFMAs free the slot.
// Live ~108 VGPR <= 128 budget (4 waves/SIMD, 1 block/CU via LDS 118.8 KB).
__global__ __launch_bounds__(1024)
__attribute__((amdgpu_waves_per_eu(4, 4)))
void fused_kernel(
    const float* __restrict__ y,
    const unsigned short* __restrict__ W2aT, const unsigned short* __restrict__ W2bT,
    float* __restrict__ out) {

    __shared__ unsigned short quadls[MROWS][QSTR]; // 74752 B; post-K reused as bf16 stage [16][2048]
    __shared__ float          yls[MROWS][36];      //  9216 B
    __shared__ unsigned short hst[16][16][68];     // 34816 B  => total 118784 B (1 block/CU)

    const int tid  = threadIdx.x;
    const int lane = tid & 63;
    const int w    = tid >> 6;                         // wave 0..15
    const int wu   = __builtin_amdgcn_readfirstlane(w);
    const int l15  = lane & 15;
    const int lg   = lane >> 4;                        // 0..3
    const int row0 = blockIdx.x * MROWS;
    unsigned short* stage = &quadls[0][0];

    // ---- Phase A: y tile (2 floats/thread, coalesced); zero hst pad cols ----
    yls[tid >> 5][tid & 31] = y[row0 * D + tid];
    yls[32 + (tid >> 5)][tid & 31] = y[row0 * D + 1024 + tid];
    {
        int rr = lane >> 2, cc0 = 48 + (lane & 3) * 4;
        *reinterpret_cast<unsigned long long*>(&hst[w][rr][cc0]) = 0ULL;
    }
    __syncthreads();

    // ---- Phase B: A build (2 (row,i) tasks/thread): quad | 1.0 | y | pad ----
    #pragma unroll
    for (int s = 0; s < 2; ++s) {
        int task = tid + s * 1024;
        int r = task >> 5, i = task & 31;
        int base = (i * (i + 1)) >> 1;
        float yi = yls[r][i];
        for (int j4 = 0; j4 <= i; j4 += 4) {
            floatx4 yv = *reinterpret_cast<const floatx4*>(&yls[r][j4]);
            #pragma unroll
            for (int jj = 0; jj < 4; ++jj) {
                int j = j4 + jj;
                if (j <= i) quadls[r][base + j] = f2bf(yi * yv[jj]);
            }
        }
        quadls[r][529 + i] = f2bf(yi);                         // y channels 529..560
        if (i == 0)  quadls[r][528] = (unsigned short)0x3F80;  // bias-one channel
        if (i < 15)  quadls[r][561 + i] = 0;                   // K-pad 561..575
    }
    __syncthreads();

    // ---- K-loop: wave w owns hidden cols [w*48, w*48+48) x 64 rows, K=576 ----
    floatx4 hacc[4][3];
    #pragma unroll
    for (int m = 0; m < 4; ++m)
        #pragma unroll
        for (int nf = 0; nf < 3; ++nf) hacc[m][nf] = (floatx4){0.f, 0.f, 0.f, 0.f};
    {
        const int KSTR = 48 * 512;
        const unsigned short* bp = W2aT + wu * 3 * 512 + lane * 8;

#define LDA(aa, mm, kx) aa = *reinterpret_cast<const short8x*>(&quadls[(mm) * 16 + l15][(kx) * 32 + lg * 8])
#define MFMA12(B0, B1, B2)                                                                 \
        {                                                                                  \
            short8x a0, a1, a2, a3;                                                        \
            LDA(a0, 0, kcur); LDA(a1, 1, kcur); LDA(a2, 2, kcur); LDA(a3, 3, kcur);        \
            hacc[0][0] = __builtin_amdgcn_mfma_f32_16x16x32_bf16(a0, B0, hacc[0][0], 0,0,0);\
            hacc[0][1] = __builtin_amdgcn_mfma_f32_16x16x32_bf16(a0, B1, hacc[0][1], 0,0,0);\
            hacc[0][2] = __builtin_amdgcn_mfma_f32_16x16x32_bf16(a0, B2, hacc[0][2], 0,0,0);\
            hacc[1][0] = __builtin_amdgcn_mfma_f32_16x16x32_bf16(a1, B0, hacc[1][0], 0,0,0);\
            hacc[1][1] = __builtin_amdgcn_mfma_f32_16x16x32_bf16(a1, B1, hacc[1][1], 0,0,0);\
            hacc[1][2] = __builtin_amdgcn_mfma_f32_16x16x32_bf16(a1, B2, hacc[1][2], 0,0,0);\
            hacc[2][0] = __builtin_amdgcn_mfma_f32_16x16x32_bf16(a2, B0, hacc[2][0], 0,0,0);\
            hacc[2][1] = __builtin_amdgcn_mfma_f32_16x16x32_bf16(a2, B1, hacc[2][1], 0,0,0);\
            hacc[2][2] = __builtin_amdgcn_mfma_f32_16x16x32_bf16(a2, B2, hacc[2][2], 0,0,0);\
            hacc[3][0] = __builtin_amdgcn_mfma_f32_16x16x32_bf16(a3, B0, hacc[3][0], 0,0,0);\
            hacc[3][1] = __builtin_amdgcn_mfma_f32_16x16x32_bf16(a3, B1, hacc[3][1], 0,0,0);\
            hacc[3][2] = __builtin_amdgcn_mfma_f32_16x16x32_bf16(a3, B2, hacc[3][2], 0,0,0);\
        }

        short8x b00, b01, b02, b10, b11, b12, b20, b21, b22;
        b00 = *reinterpret_cast<const short8x*>(bp);
        b01 = *reinterpret_cast<const short8x*>(bp + 512);
        b02 = *reinterpret_cast<const short8x*>(bp + 1024);
        b10 = *reinterpret_cast<const short8x*>(bp + KSTR);
        b11 = *reinterpret_cast<const short8x*>(bp + KSTR + 512);
        b12 = *reinterpret_cast<const short8x*>(bp + KSTR + 1024);
        b20 = *reinterpret_cast<const short8x*>(bp + 2 * KSTR);
        b21 = *reinterpret_cast<const short8x*>(bp + 2 * KSTR + 512);
        b22 = *reinterpret_cast<const short8x*>(bp + 2 * KSTR + 1024);
        bp += 3 * KSTR;   // bp now points at k = 3

        #pragma unroll 1
        for (int kk = 0; kk < 6; ++kk) {
            int kcur = kk * 3;
            MFMA12(b00, b01, b02);                 // consume k
            if (kk != 5) {                         // prefetch k+3 into freed slot
                b00 = *reinterpret_cast<const short8x*>(bp);
                b01 = *reinterpret_cast<const short8x*>(bp + 512);
                b02 = *reinterpret_cast<const short8x*>(bp + 1024);
            }
            kcur = kk * 3 + 1;
            MFMA12(b10, b11, b12);                 // consume k+1
            if (kk != 5) {                         // prefetch k+4
                b10 = *reinterpret_cast<const short8x*>(bp + KSTR);
                b11 = *reinterpret_cast<const short8x*>(bp + KSTR + 512);
                b12 = *reinterpret_cast<const short8x*>(bp + KSTR + 1024);
            }
            kcur = kk * 3 + 2;
            MFMA12(b20, b21, b22);                 // consume k+2
            if (kk != 5) {                         // prefetch k+5
                b20 = *reinterpret_cast<const short8x*>(bp + 2 * KSTR);
                b21 = *reinterpret_cast<const short8x*>(bp + 2 * KSTR + 512);
                b22 = *reinterpret_cast<const short8x*>(bp + 2 * KSTR + 1024);
                bp += 3 * KSTR;
            }
        }
#undef LDA
#undef MFMA12
    }
    __syncthreads();   // all quadls K-reads complete -> stage region free

    // ---- epilogue: per m-tile: tanh -> hst -> GEMM2 (transient o2) -> packed stage ----
    // stage layout: panel wu (2048 ushorts): flat = row*32 + 2*l15 + of
    {
        const unsigned short* wb = W2bT + wu * 4 * 512 + lane * 8;
        #pragma unroll
        for (int m = 0; m < 4; ++m) {
            #pragma unroll
            for (int r = 0; r < 4; ++r) {
                hst[w][lg * 4 + r][l15]      = f2bf(tanh_fast(hacc[m][0][r]));
                hst[w][lg * 4 + r][16 + l15] = f2bf(tanh_fast(hacc[m][1][r]));
                hst[w][lg * 4 + r][32 + l15] = f2bf(tanh_fast(hacc[m][2][r]));
            }
            short8x aa0 = *reinterpret_cast<const short8x*>(&hst[w][l15][lg * 8]);
            short8x aa1 = *reinterpret_cast<const short8x*>(&hst[w][l15][32 + lg * 8]);
            floatx4 o20 = {0,0,0,0}, o21 = {0,0,0,0};
            {
                short8x bw00 = *reinterpret_cast<const short8x*>(wb);
                short8x bw01 = *reinterpret_cast<const short8x*>(wb + 512);
                o20 = __builtin_amdgcn_mfma_f32_16x16x32_bf16(aa0, bw00, o20, 0, 0, 0);
                o21 = __builtin_amdgcn_mfma_f32_16x16x32_bf16(aa0, bw01, o21, 0, 0, 0);
            }
            {
                short8x bw10 = *reinterpret_cast<const short8x*>(wb + 1024);
                short8x bw11 = *reinterpret_cast<const short8x*>(wb + 1536);
                o20 = __builtin_amdgcn_mfma_f32_16x16x32_bf16(aa1, bw10, o20, 0, 0, 0);
                o21 = __builtin_amdgcn_mfma_f32_16x16x32_bf16(aa1, bw11, o21, 0, 0, 0);
            }
            #pragma unroll
            for (int r = 0; r < 4; ++r) {
                int row = m * 16 + lg * 4 + r;
                unsigned int pk = ((unsigned int)f2bf(o21[r]) << 16) | (unsigned int)f2bf(o20[r]);
                *reinterpret_cast<unsigned int*>(&stage[wu * 2048 + row * 32 + l15 * 2]) = pk;
            }
        }
    }
    __syncthreads();   // all stage writes visible

    // ---- reduce 16 bf16 panels (biases inside), 2 outputs/thread ----
    {
        #pragma unroll
        for (int s = 0; s < 2; ++s) {
            int e  = tid + s * 1024;
            int c  = e & 31;
            int fr = (e & ~31) + ((c & 15) << 1) + (c >> 4);   // packed-layout remap
            float s0 = 0.f, s1 = 0.f;
            #pragma unroll
            for (int p = 0; p < 16; p += 2) {
                s0 += bf2f(stage[p * 2048 + fr]);
                s1 += bf2f(stage[(p + 1) * 2048 + fr]);
            }
            out[row0 * D + e] = s0 + s1;
        }
    }
}

extern "C" void kernel_launch(void* const* d_in, const int* in_sizes, int n_in,
                              void* d_out, int out_size, void* d_ws, size_t ws_size,
                              hipStream_t stream) {
    const float* y   = (const float*)d_in[1];
    const float* W1a = (const float*)d_in[2];
    const float* b1a = (const float*)d_in[3];
    const float* W1b = (const float*)d_in[4];
    const float* b1b = (const float*)d_in[5];
    const float* W2a = (const float*)d_in[6];
    const float* b2a = (const float*)d_in[7];
    const float* W2b = (const float*)d_in[8];
    const float* b2b = (const float*)d_in[9];

    unsigned short* W2aT = (unsigned short*)d_ws;                      // 884736 B
    unsigned short* W2bT = (unsigned short*)((char*)d_ws + 884736);    //  65536 B

    const int prep_tasks = KITER * 48 * 512 + 16 * 4 * 512;            // 475136
    prep_kernel<<<(prep_tasks + 255) / 256, 256, 0, stream>>>(
        W2a, b2a, W2b, W1a, b1a, W1b, b1b, b2b, W2aT, W2bT);
    fused_kernel<<<B_TOT / MROWS, 1024, 0, stream>>>(y, W2aT, W2bT, (float*)d_out);
}

// Round 16
// 150.060 us; speedup vs baseline: 1.2657x; 1.0008x over previous
//
#include <hip/hip_runtime.h>
#include <hip/hip_bf16.h>

#define B_TOT 131072
#define D     32
#define H1    50
#define QF    528      // tril feature count
#define H2    700
#define MROWS 64       // batch rows per block
#define QSTR  584      // quadls row stride (ushorts)
#define KITER 18       // K = 576 = 528 quad | 1 bias-one | 32 y | 15 pad
// extended hidden layout (768 cols): 0..699 net2 hidden, 700..749 net1 hidden,
// 750 bias channel (h==1.0), 751..767 zero pad

typedef __attribute__((ext_vector_type(8))) short  short8x;
typedef __attribute__((ext_vector_type(4))) float  floatx4;
typedef __attribute__((ext_vector_type(4))) unsigned int uint4x;

static __device__ __forceinline__ unsigned short f2bf(float f) {
    __hip_bfloat16 h = __float2bfloat16(f);   // RNE
    return __builtin_bit_cast(unsigned short, h);
}
static __device__ __forceinline__ float bf2f(unsigned short u) {
    unsigned int x = (unsigned int)u << 16;
    return __builtin_bit_cast(float, x);
}
// clampless tanh; MUST stay bit-identical between prep (bias channel) and epilogue.
static __device__ __forceinline__ float tanh_fast(float x) {
    float e = __builtin_amdgcn_exp2f(x * 2.885390082f);   // e^(2x)
    return 1.f - 2.f * __builtin_amdgcn_rcpf(e + 1.f);
}

// ---------------- prep: extended pre-fragmented bf16 weight layouts (r11, unchanged) ----
__global__ void prep_kernel(const float* __restrict__ W2a, const float* __restrict__ b2a,
                            const float* __restrict__ W2b,
                            const float* __restrict__ W1a, const float* __restrict__ b1a,
                            const float* __restrict__ W1b, const float* __restrict__ b1b,
                            const float* __restrict__ b2b,
                            unsigned short* __restrict__ W2aT,
                            unsigned short* __restrict__ W2bT) {
    int idx = blockIdx.x * 256 + threadIdx.x;
    const int N1 = KITER * 48 * 512;   // 442368
    const int N2 = 16 * 4 * 512;       // 32768
    if (idx < N1) {
        int k   = idx / (48 * 512);
        int rem = idx - k * (48 * 512);
        int p   = rem >> 9;
        int q   = rem & 511;
        int ln  = q >> 3, j = q & 7;
        int kk  = k * 32 + ((ln >> 4) << 3) + j;
        int c   = (p << 4) + (ln & 15);
        float v = 0.f;
        if (c < H2) {
            if (kk < QF)       v = W2a[kk * H2 + c];
            else if (kk == QF) v = b2a[c];
        } else if (c < H2 + H1) {
            int cc = c - H2;
            if (kk == QF)                        v = b1a[cc];
            else if (kk > QF && kk < QF + 1 + D) v = W1a[(kk - QF - 1) * H1 + cc];
        } else if (c == H2 + H1) {
            if (kk == QF) v = 1.0f;
        }
        W2aT[idx] = f2bf(v);
    } else if (idx < N1 + N2) {
        int i2 = idx - N1;
        int q  = i2 & 511;
        int ln = q >> 3, j = q & 7;
        int w  = i2 >> 11;
        int ks = (i2 >> 10) & 1;
        int of = (i2 >> 9) & 1;
        int kl = (ks << 5) + ((ln >> 4) << 3) + j;   // local k 0..63
        int kg = w * 48 + kl;
        int c  = (of << 4) + (ln & 15);
        float v = 0.f;
        if (kl < 48) {
            if (kg < H2)            v = W2b[kg * D + c];
            else if (kg < H2 + H1)  v = W1b[(kg - H2) * D + c];
            else if (kg == H2 + H1) v = (b1b[c] + b2b[c]) / tanh_fast(1.0f);
        }
        W2bT[i2] = f2bf(v);
    }
}

// ---------------- fused main kernel ----------------
// r15 with the stage-layout collision FIXED: per 4-row group the pk footprint
// is 16 c * 4 r * 2 ushorts = 128 ushorts, so the lane offset is l15*8 (write)
// / c*8 (read). r15's l15*16 made lg-group g's lanes 8..15 overwrite group
// g+1's lanes 0..7 (absmax 15.1). Wave write pattern is now one contiguous
// 1KB region, 16B/lane -> conflict-free b128.
//  (a) hst stride 72 ushorts (144 B = 9*16): aligned b128 aa reads.
//  (b) stage: ONE b128 per m (4 packed u32, r=0..3).
//  (c) reduce: packed u32 -> both output cols, 4-way chains.
__global__ __launch_bounds__(1024)
__attribute__((amdgpu_waves_per_eu(4, 4)))
void fused_kernel(
    const float* __restrict__ y,
    const unsigned short* __restrict__ W2aT, const unsigned short* __restrict__ W2bT,
    float* __restrict__ out) {

    __shared__ unsigned short quadls[MROWS][QSTR]; // 74752 B; post-K reused as bf16 stage [16][2048]
    __shared__ float          yls[MROWS][36];      //  9216 B
    __shared__ unsigned short hst[16][16][72];     // 36864 B  => total 120832 B (1 block/CU)

    const int tid  = threadIdx.x;
    const int lane = tid & 63;
    const int w    = tid >> 6;                         // wave 0..15
    const int wu   = __builtin_amdgcn_readfirstlane(w);
    const int l15  = lane & 15;
    const int lg   = lane >> 4;                        // 0..3
    const int row0 = blockIdx.x * MROWS;
    unsigned short* stage = &quadls[0][0];

    // ---- Phase A: y tile (2 floats/thread, coalesced); zero hst pad cols ----
    yls[tid >> 5][tid & 31] = y[row0 * D + tid];
    yls[32 + (tid >> 5)][tid & 31] = y[row0 * D + 1024 + tid];
    {
        int rr = lane >> 2, cc0 = 48 + (lane & 3) * 4;
        *reinterpret_cast<unsigned long long*>(&hst[w][rr][cc0]) = 0ULL;
    }
    __syncthreads();

    // ---- Phase B: A build (2 (row,i) tasks/thread): quad | 1.0 | y | pad ----
    #pragma unroll
    for (int s = 0; s < 2; ++s) {
        int task = tid + s * 1024;
        int r = task >> 5, i = task & 31;
        int base = (i * (i + 1)) >> 1;
        float yi = yls[r][i];
        for (int j4 = 0; j4 <= i; j4 += 4) {
            floatx4 yv = *reinterpret_cast<const floatx4*>(&yls[r][j4]);
            #pragma unroll
            for (int jj = 0; jj < 4; ++jj) {
                int j = j4 + jj;
                if (j <= i) quadls[r][base + j] = f2bf(yi * yv[jj]);
            }
        }
        quadls[r][529 + i] = f2bf(yi);                         // y channels 529..560
        if (i == 0)  quadls[r][528] = (unsigned short)0x3F80;  // bias-one channel
        if (i < 15)  quadls[r][561 + i] = 0;                   // K-pad 561..575
    }
    __syncthreads();

    // ---- K-loop: wave w owns hidden cols [w*48, w*48+48) x 64 rows, K=576 ----
    floatx4 hacc[4][3];
    #pragma unroll
    for (int m = 0; m < 4; ++m)
        #pragma unroll
        for (int nf = 0; nf < 3; ++nf) hacc[m][nf] = (floatx4){0.f, 0.f, 0.f, 0.f};
    {
        const unsigned short* bp = W2aT + wu * 3 * 512 + lane * 8;
        #pragma unroll 2
        for (int k = 0; k < KITER; ++k) {
            short8x a[4];
            #pragma unroll
            for (int m = 0; m < 4; ++m)
                a[m] = *reinterpret_cast<const short8x*>(&quadls[m * 16 + l15][k * 32 + lg * 8]);
            short8x b0 = *reinterpret_cast<const short8x*>(bp);
            short8x b1 = *reinterpret_cast<const short8x*>(bp + 512);
            short8x b2 = *reinterpret_cast<const short8x*>(bp + 1024);
            #pragma unroll
            for (int m = 0; m < 4; ++m) {
                hacc[m][0] = __builtin_amdgcn_mfma_f32_16x16x32_bf16(a[m], b0, hacc[m][0], 0, 0, 0);
                hacc[m][1] = __builtin_amdgcn_mfma_f32_16x16x32_bf16(a[m], b1, hacc[m][1], 0, 0, 0);
                hacc[m][2] = __builtin_amdgcn_mfma_f32_16x16x32_bf16(a[m], b2, hacc[m][2], 0, 0, 0);
            }
            bp += 48 * 512;
        }
    }
    __syncthreads();   // all quadls K-reads complete -> stage region free

    // ---- epilogue: per m-tile: tanh -> hst -> GEMM2 (transient o2) -> b128 stage ----
    // stage layout (ushort idx in panel wu): (row&~3)*32 + c*8 + (row&3)*2 + of
    // per (m,lg): lane l15 writes ONE b128 (4 pk u32s, r=0..3) at group*32 + l15*8.
    {
        const unsigned short* wb = W2bT + wu * 4 * 512 + lane * 8;
        #pragma unroll
        for (int m = 0; m < 4; ++m) {
            #pragma unroll
            for (int r = 0; r < 4; ++r) {
                hst[w][lg * 4 + r][l15]      = f2bf(tanh_fast(hacc[m][0][r]));
                hst[w][lg * 4 + r][16 + l15] = f2bf(tanh_fast(hacc[m][1][r]));
                hst[w][lg * 4 + r][32 + l15] = f2bf(tanh_fast(hacc[m][2][r]));
            }
            short8x aa0 = *reinterpret_cast<const short8x*>(&hst[w][l15][lg * 8]);
            short8x aa1 = *reinterpret_cast<const short8x*>(&hst[w][l15][32 + lg * 8]);
            floatx4 o20 = {0,0,0,0}, o21 = {0,0,0,0};
            {
                short8x bw00 = *reinterpret_cast<const short8x*>(wb);
                short8x bw01 = *reinterpret_cast<const short8x*>(wb + 512);
                o20 = __builtin_amdgcn_mfma_f32_16x16x32_bf16(aa0, bw00, o20, 0, 0, 0);
                o21 = __builtin_amdgcn_mfma_f32_16x16x32_bf16(aa0, bw01, o21, 0, 0, 0);
            }
            {
                short8x bw10 = *reinterpret_cast<const short8x*>(wb + 1024);
                short8x bw11 = *reinterpret_cast<const short8x*>(wb + 1536);
                o20 = __builtin_amdgcn_mfma_f32_16x16x32_bf16(aa1, bw10, o20, 0, 0, 0);
                o21 = __builtin_amdgcn_mfma_f32_16x16x32_bf16(aa1, bw11, o21, 0, 0, 0);
            }
            uint4x pk;
            #pragma unroll
            for (int r = 0; r < 4; ++r)
                pk[r] = ((unsigned int)f2bf(o21[r]) << 16) | (unsigned int)f2bf(o20[r]);
            *reinterpret_cast<uint4x*>(
                &stage[wu * 2048 + (m * 16 + lg * 4) * 32 + l15 * 8]) = pk;
        }
    }
    __syncthreads();   // all stage writes visible

    // ---- reduce 16 bf16 panels: 1 packed u32/panel -> both output cols ----
    {
        int row = tid >> 4, c = tid & 15;
        int fr = (row & ~3) * 32 + c * 8 + (row & 3) * 2;    // ushort idx of pk
        float a0 = 0.f, a1 = 0.f, a2 = 0.f, a3 = 0.f;        // col c chains
        float b0 = 0.f, b1 = 0.f, b2 = 0.f, b3 = 0.f;        // col c+16 chains
        #pragma unroll
        for (int p = 0; p < 16; p += 4) {
            unsigned int v0 = *reinterpret_cast<const unsigned int*>(&stage[p * 2048 + fr]);
            unsigned int v1 = *reinterpret_cast<const unsigned int*>(&stage[(p + 1) * 2048 + fr]);
            unsigned int v2 = *reinterpret_cast<const unsigned int*>(&stage[(p + 2) * 2048 + fr]);
            unsigned int v3 = *reinterpret_cast<const unsigned int*>(&stage[(p + 3) * 2048 + fr]);
            a0 += bf2f((unsigned short)(v0 & 0xffff));  b0 += bf2f((unsigned short)(v0 >> 16));
            a1 += bf2f((unsigned short)(v1 & 0xffff));  b1 += bf2f((unsigned short)(v1 >> 16));
            a2 += bf2f((unsigned short)(v2 & 0xffff));  b2 += bf2f((unsigned short)(v2 >> 16));
            a3 += bf2f((unsigned short)(v3 & 0xffff));  b3 += bf2f((unsigned short)(v3 >> 16));
        }
        out[row0 * D + row * 32 + c]      = (a0 + a1) + (a2 + a3);
        out[row0 * D + row * 32 + c + 16] = (b0 + b1) + (b2 + b3);
    }
}

extern "C" void kernel_launch(void* const* d_in, const int* in_sizes, int n_in,
                              void* d_out, int out_size, void* d_ws, size_t ws_size,
                              hipStream_t stream) {
    const float* y   = (const float*)d_in[1];
    const float* W1a = (const float*)d_in[2];
    const float* b1a = (const float*)d_in[3];
    const float* W1b = (const float*)d_in[4];
    const float* b1b = (const float*)d_in[5];
    const float* W2a = (const float*)d_in[6];
    const float* b2a = (const float*)d_in[7];
    const float* W2b = (const float*)d_in[8];
    const float* b2b = (const float*)d_in[9];

    unsigned short* W2aT = (unsigned short*)d_ws;                      // 884736 B
    unsigned short* W2bT = (unsigned short*)((char*)d_ws + 884736);    //  65536 B

    const int prep_tasks = KITER * 48 * 512 + 16 * 4 * 512;            // 475136
    prep_kernel<<<(prep_tasks + 255) / 256, 256, 0, stream>>>(
        W2a, b2a, W2b, W1a, b1a, W1b, b1b, b2b, W2aT, W2bT);
    fused_kernel<<<B_TOT / MROWS, 1024, 0, stream>>>(y, W2aT, W2bT, (float*)d_out);
}

// Round 17
// 149.951 us; speedup vs baseline: 1.2666x; 1.0007x over previous
//
#include <hip/hip_runtime.h>
#include <hip/hip_bf16.h>

#define B_TOT 131072
#define D     32
#define H1    50
#define QF    528      // tril feature count
#define H2    700
#define MROWS 64       // batch rows per block
#define QSTR  584      // quadls row stride (ushorts)
#define KITER 18       // K = 576 = 528 quad | 1 bias-one | 32 y | 15 pad
// extended hidden layout (768 cols): 0..699 net2 hidden, 700..749 net1 hidden,
// 750 bias channel (h==1.0), 751..767 zero pad

typedef __attribute__((ext_vector_type(8))) short  short8x;
typedef __attribute__((ext_vector_type(4))) float  floatx4;
typedef __attribute__((ext_vector_type(4))) unsigned int uint4x;

static __device__ __forceinline__ unsigned short f2bf(float f) {
    __hip_bfloat16 h = __float2bfloat16(f);   // RNE
    return __builtin_bit_cast(unsigned short, h);
}
static __device__ __forceinline__ float bf2f(unsigned short u) {
    unsigned int x = (unsigned int)u << 16;
    return __builtin_bit_cast(float, x);
}
// clampless tanh; MUST stay bit-identical between prep (bias channel) and epilogue.
static __device__ __forceinline__ float tanh_fast(float x) {
    float e = __builtin_amdgcn_exp2f(x * 2.885390082f);   // e^(2x)
    return 1.f - 2.f * __builtin_amdgcn_rcpf(e + 1.f);
}

// ---------------- prep: extended pre-fragmented bf16 weight layouts (r11, unchanged) ----
__global__ void prep_kernel(const float* __restrict__ W2a, const float* __restrict__ b2a,
                            const float* __restrict__ W2b,
                            const float* __restrict__ W1a, const float* __restrict__ b1a,
                            const float* __restrict__ W1b, const float* __restrict__ b1b,
                            const float* __restrict__ b2b,
                            unsigned short* __restrict__ W2aT,
                            unsigned short* __restrict__ W2bT) {
    int idx = blockIdx.x * 256 + threadIdx.x;
    const int N1 = KITER * 48 * 512;   // 442368
    const int N2 = 16 * 4 * 512;       // 32768
    if (idx < N1) {
        int k   = idx / (48 * 512);
        int rem = idx - k * (48 * 512);
        int p   = rem >> 9;
        int q   = rem & 511;
        int ln  = q >> 3, j = q & 7;
        int kk  = k * 32 + ((ln >> 4) << 3) + j;
        int c   = (p << 4) + (ln & 15);
        float v = 0.f;
        if (c < H2) {
            if (kk < QF)       v = W2a[kk * H2 + c];
            else if (kk == QF) v = b2a[c];
        } else if (c < H2 + H1) {
            int cc = c - H2;
            if (kk == QF)                        v = b1a[cc];
            else if (kk > QF && kk < QF + 1 + D) v = W1a[(kk - QF - 1) * H1 + cc];
        } else if (c == H2 + H1) {
            if (kk == QF) v = 1.0f;
        }
        W2aT[idx] = f2bf(v);
    } else if (idx < N1 + N2) {
        int i2 = idx - N1;
        int q  = i2 & 511;
        int ln = q >> 3, j = q & 7;
        int w  = i2 >> 11;
        int ks = (i2 >> 10) & 1;
        int of = (i2 >> 9) & 1;
        int kl = (ks << 5) + ((ln >> 4) << 3) + j;   // local k 0..63
        int kg = w * 48 + kl;
        int c  = (of << 4) + (ln & 15);
        float v = 0.f;
        if (kl < 48) {
            if (kg < H2)            v = W2b[kg * D + c];
            else if (kg < H2 + H1)  v = W1b[(kg - H2) * D + c];
            else if (kg == H2 + H1) v = (b1b[c] + b2b[c]) / tanh_fast(1.0f);
        }
        W2bT[i2] = f2bf(v);
    }
}

// ---------------- fused main kernel ----------------
// r15 with the stage-layout collision FIXED: per 4-row group the pk footprint
// is 16 c * 4 r * 2 ushorts = 128 ushorts, so the lane offset is l15*8 (write)
// / c*8 (read). r15's l15*16 made lg-group g's lanes 8..15 overwrite group
// g+1's lanes 0..7 (absmax 15.1). Wave write pattern is now one contiguous
// 1KB region, 16B/lane -> conflict-free b128.
//  (a) hst stride 72 ushorts (144 B = 9*16): aligned b128 aa reads.
//  (b) stage: ONE b128 per m (4 packed u32, r=0..3).
//  (c) reduce: packed u32 -> both output cols, 4-way chains.
__global__ __launch_bounds__(1024)
__attribute__((amdgpu_waves_per_eu(4, 4)))
void fused_kernel(
    const float* __restrict__ y,
    const unsigned short* __restrict__ W2aT, const unsigned short* __restrict__ W2bT,
    float* __restrict__ out) {

    __shared__ unsigned short quadls[MROWS][QSTR]; // 74752 B; post-K reused as bf16 stage [16][2048]
    __shared__ float          yls[MROWS][36];      //  9216 B
    __shared__ unsigned short hst[16][16][72];     // 36864 B  => total 120832 B (1 block/CU)

    const int tid  = threadIdx.x;
    const int lane = tid & 63;
    const int w    = tid >> 6;                         // wave 0..15
    const int wu   = __builtin_amdgcn_readfirstlane(w);
    const int l15  = lane & 15;
    const int lg   = lane >> 4;                        // 0..3
    const int row0 = blockIdx.x * MROWS;
    unsigned short* stage = &quadls[0][0];

    // ---- Phase A: y tile (2 floats/thread, coalesced); zero hst pad cols ----
    yls[tid >> 5][tid & 31] = y[row0 * D + tid];
    yls[32 + (tid >> 5)][tid & 31] = y[row0 * D + 1024 + tid];
    {
        int rr = lane >> 2, cc0 = 48 + (lane & 3) * 4;
        *reinterpret_cast<unsigned long long*>(&hst[w][rr][cc0]) = 0ULL;
    }
    __syncthreads();

    // ---- Phase B: A build (2 (row,i) tasks/thread): quad | 1.0 | y | pad ----
    #pragma unroll
    for (int s = 0; s < 2; ++s) {
        int task = tid + s * 1024;
        int r = task >> 5, i = task & 31;
        int base = (i * (i + 1)) >> 1;
        float yi = yls[r][i];
        for (int j4 = 0; j4 <= i; j4 += 4) {
            floatx4 yv = *reinterpret_cast<const floatx4*>(&yls[r][j4]);
            #pragma unroll
            for (int jj = 0; jj < 4; ++jj) {
                int j = j4 + jj;
                if (j <= i) quadls[r][base + j] = f2bf(yi * yv[jj]);
            }
        }
        quadls[r][529 + i] = f2bf(yi);                         // y channels 529..560
        if (i == 0)  quadls[r][528] = (unsigned short)0x3F80;  // bias-one channel
        if (i < 15)  quadls[r][561 + i] = 0;                   // K-pad 561..575
    }
    __syncthreads();

    // ---- K-loop: wave w owns hidden cols [w*48, w*48+48) x 64 rows, K=576 ----
    floatx4 hacc[4][3];
    #pragma unroll
    for (int m = 0; m < 4; ++m)
        #pragma unroll
        for (int nf = 0; nf < 3; ++nf) hacc[m][nf] = (floatx4){0.f, 0.f, 0.f, 0.f};
    {
        const unsigned short* bp = W2aT + wu * 3 * 512 + lane * 8;
        #pragma unroll 2
        for (int k = 0; k < KITER; ++k) {
            short8x a[4];
            #pragma unroll
            for (int m = 0; m < 4; ++m)
                a[m] = *reinterpret_cast<const short8x*>(&quadls[m * 16 + l15][k * 32 + lg * 8]);
            short8x b0 = *reinterpret_cast<const short8x*>(bp);
            short8x b1 = *reinterpret_cast<const short8x*>(bp + 512);
            short8x b2 = *reinterpret_cast<const short8x*>(bp + 1024);
            #pragma unroll
            for (int m = 0; m < 4; ++m) {
                hacc[m][0] = __builtin_amdgcn_mfma_f32_16x16x32_bf16(a[m], b0, hacc[m][0], 0, 0, 0);
                hacc[m][1] = __builtin_amdgcn_mfma_f32_16x16x32_bf16(a[m], b1, hacc[m][1], 0, 0, 0);
                hacc[m][2] = __builtin_amdgcn_mfma_f32_16x16x32_bf16(a[m], b2, hacc[m][2], 0, 0, 0);
            }
            bp += 48 * 512;
        }
    }
    __syncthreads();   // all quadls K-reads complete -> stage region free

    // ---- epilogue: per m-tile: tanh -> hst -> GEMM2 (transient o2) -> b128 stage ----
    // stage layout (ushort idx in panel wu): (row&~3)*32 + c*8 + (row&3)*2 + of
    // per (m,lg): lane l15 writes ONE b128 (4 pk u32s, r=0..3) at group*32 + l15*8.
    {
        const unsigned short* wb = W2bT + wu * 4 * 512 + lane * 8;
        #pragma unroll
        for (int m = 0; m < 4; ++m) {
            #pragma unroll
            for (int r = 0; r < 4; ++r) {
                hst[w][lg * 4 + r][l15]      = f2bf(tanh_fast(hacc[m][0][r]));
                hst[w][lg * 4 + r][16 + l15] = f2bf(tanh_fast(hacc[m][1][r]));
                hst[w][lg * 4 + r][32 + l15] = f2bf(tanh_fast(hacc[m][2][r]));
            }
            short8x aa0 = *reinterpret_cast<const short8x*>(&hst[w][l15][lg * 8]);
            short8x aa1 = *reinterpret_cast<const short8x*>(&hst[w][l15][32 + lg * 8]);
            floatx4 o20 = {0,0,0,0}, o21 = {0,0,0,0};
            {
                short8x bw00 = *reinterpret_cast<const short8x*>(wb);
                short8x bw01 = *reinterpret_cast<const short8x*>(wb + 512);
                o20 = __builtin_amdgcn_mfma_f32_16x16x32_bf16(aa0, bw00, o20, 0, 0, 0);
                o21 = __builtin_amdgcn_mfma_f32_16x16x32_bf16(aa0, bw01, o21, 0, 0, 0);
            }
            {
                short8x bw10 = *reinterpret_cast<const short8x*>(wb + 1024);
                short8x bw11 = *reinterpret_cast<const short8x*>(wb + 1536);
                o20 = __builtin_amdgcn_mfma_f32_16x16x32_bf16(aa1, bw10, o20, 0, 0, 0);
                o21 = __builtin_amdgcn_mfma_f32_16x16x32_bf16(aa1, bw11, o21, 0, 0, 0);
            }
            uint4x pk;
            #pragma unroll
            for (int r = 0; r < 4; ++r)
                pk[r] = ((unsigned int)f2bf(o21[r]) << 16) | (unsigned int)f2bf(o20[r]);
            *reinterpret_cast<uint4x*>(
                &stage[wu * 2048 + (m * 16 + lg * 4) * 32 + l15 * 8]) = pk;
        }
    }
    __syncthreads();   // all stage writes visible

    // ---- reduce 16 bf16 panels: 1 packed u32/panel -> both output cols ----
    {
        int row = tid >> 4, c = tid & 15;
        int fr = (row & ~3) * 32 + c * 8 + (row & 3) * 2;    // ushort idx of pk
        float a0 = 0.f, a1 = 0.f, a2 = 0.f, a3 = 0.f;        // col c chains
        float b0 = 0.f, b1 = 0.f, b2 = 0.f, b3 = 0.f;        // col c+16 chains
        #pragma unroll
        for (int p = 0; p < 16; p += 4) {
            unsigned int v0 = *reinterpret_cast<const unsigned int*>(&stage[p * 2048 + fr]);
            unsigned int v1 = *reinterpret_cast<const unsigned int*>(&stage[(p + 1) * 2048 + fr]);
            unsigned int v2 = *reinterpret_cast<const unsigned int*>(&stage[(p + 2) * 2048 + fr]);
            unsigned int v3 = *reinterpret_cast<const unsigned int*>(&stage[(p + 3) * 2048 + fr]);
            a0 += bf2f((unsigned short)(v0 & 0xffff));  b0 += bf2f((unsigned short)(v0 >> 16));
            a1 += bf2f((unsigned short)(v1 & 0xffff));  b1 += bf2f((unsigned short)(v1 >> 16));
            a2 += bf2f((unsigned short)(v2 & 0xffff));  b2 += bf2f((unsigned short)(v2 >> 16));
            a3 += bf2f((unsigned short)(v3 & 0xffff));  b3 += bf2f((unsigned short)(v3 >> 16));
        }
        out[row0 * D + row * 32 + c]      = (a0 + a1) + (a2 + a3);
        out[row0 * D + row * 32 + c + 16] = (b0 + b1) + (b2 + b3);
    }
}

extern "C" void kernel_launch(void* const* d_in, const int* in_sizes, int n_in,
                              void* d_out, int out_size, void* d_ws, size_t ws_size,
                              hipStream_t stream) {
    const float* y   = (const float*)d_in[1];
    const float* W1a = (const float*)d_in[2];
    const float* b1a = (const float*)d_in[3];
    const float* W1b = (const float*)d_in[4];
    const float* b1b = (const float*)d_in[5];
    const float* W2a = (const float*)d_in[6];
    const float* b2a = (const float*)d_in[7];
    const float* W2b = (const float*)d_in[8];
    const float* b2b = (const float*)d_in[9];

    unsigned short* W2aT = (unsigned short*)d_ws;                      // 884736 B
    unsigned short* W2bT = (unsigned short*)((char*)d_ws + 884736);    //  65536 B

    const int prep_tasks = KITER * 48 * 512 + 16 * 4 * 512;            // 475136
    prep_kernel<<<(prep_tasks + 255) / 256, 256, 0, stream>>>(
        W2a, b2a, W2b, W1a, b1a, W1b, b1b, b2b, W2aT, W2bT);
    fused_kernel<<<B_TOT / MROWS, 1024, 0, stream>>>(y, W2aT, W2bT, (float*)d_out);
}